// Round 7
// baseline (197.668 us; speedup 1.0000x reference)
//
#include <hip/hip_runtime.h>
#include <hip/hip_bf16.h>
#include <math.h>

#define NP 1024
#define R 32
#define C 16
#define GAMMA (32.0f/3.5f)
#define DC (3.5f/31.0f)

typedef __attribute__((ext_vector_type(8))) short bf16x8;
typedef __attribute__((ext_vector_type(4))) float f32x4;
typedef __attribute__((ext_vector_type(4))) unsigned u32x4;

// Fast RNE float->bf16 for FINITE values (no NaN path).
__device__ __forceinline__ unsigned bfbits(float x){
    unsigned u = __builtin_bit_cast(unsigned, x);
    return u + 0x7FFFu + ((u >> 16) & 1u);
}
__device__ __forceinline__ short tobf(float x){
    return (short)(bfbits(x) >> 16);
}
__device__ __forceinline__ float frombf(short s){
    const unsigned u = ((unsigned)(unsigned short)s) << 16;
    return __builtin_bit_cast(float, u);
}
__device__ __forceinline__ unsigned pack2bf(float a, float b){
    return (bfbits(a) >> 16) | (bfbits(b) & 0xFFFF0000u);
}
__device__ __forceinline__ float eluf(float x){ return x > 0.f ? x : expm1f(x); }

__device__ __forceinline__ f32x4 mfma16(bf16x8 a, bf16x8 b, f32x4 c){
    return __builtin_amdgcn_mfma_f32_16x16x32_bf16(a, b, c, 0, 0, 0);
}

// rbf A-fragment for row-distance dij, k = q*8 + jj.
__device__ __forceinline__ bf16x8 make_afrag(float dij, int q){
    u32x4 av;
    #pragma unroll
    for (int p = 0; p < 4; p++){
        const float t0 = dij - (float)(q*8 + 2*p)*DC;
        const float t1 = dij - (float)(q*8 + 2*p + 1)*DC;
        av[p] = pack2bf(__expf(-GAMMA*t0*t0), __expf(-GAMMA*t1*t1));
    }
    return __builtin_bit_cast(bf16x8, av);
}

// B-operand fragment: element jj = src[(q*8+jj)*STRIDE + n]; bf16 hi+lo split.
template<int STRIDE>
__device__ __forceinline__ void load_bfrag(const float* __restrict__ src, int q, int n,
                                           bf16x8& hi, bf16x8& lo){
    #pragma unroll
    for (int jj = 0; jj < 8; jj++){
        const float w = src[(q*8+jj)*STRIDE + n];
        const short h = tobf(w);
        hi[jj] = h;
        lo[jj] = tobf(w - frombf(h));
    }
}

// ---------------------------------------------------------------------------
// Layer 1 (MFMA, barrier-free, split-K x2, SW-pipelined point loads).
// ---------------------------------------------------------------------------
__global__ __launch_bounds__(256) void k_layer1(
    const float* __restrict__ points,
    const float* __restrict__ W1, const float* __restrict__ B1,
    const float* __restrict__ W2, const float* __restrict__ B2,
    float* __restrict__ out0h, float* __restrict__ out1h)
{
    __shared__ float sS0[4][32];
    __shared__ float sT[4][32][3];
    __shared__ float sUp[4][3];

    const int tid  = threadIdx.x;
    const int lane = tid & 63;
    const int wv   = tid >> 6;
    const int l16  = lane & 15;
    const int q    = lane >> 4;
    const int a    = blockIdx.x >> 1;
    const int half = blockIdx.x & 1;
    const float pax = points[a*3+0], pay = points[a*3+1], paz = points[a*3+2];

    bf16x8 w1hi[2][2], w1lo[2][2];
    float  b1v[2][2];
    #pragma unroll
    for (int fi = 0; fi < 2; fi++)
        #pragma unroll
        for (int nt = 0; nt < 2; nt++){
            load_bfrag<R>(W1 + fi*R*R, q, nt*16 + l16, w1hi[fi][nt], w1lo[fi][nt]);
            b1v[fi][nt] = B1[fi*R + nt*16 + l16];
        }

    float s0a[2] = {0.f, 0.f};
    float T[2][3] = {};
    float upx = 0.f, upy = 0.f, upz = 0.f;

    // prologue prefetch (tile it=0)
    float cpx, cpy, cpz;
    {
        const int bA0 = (half*8)*64 + wv*16 + l16;
        cpx = points[bA0*3+0]; cpy = points[bA0*3+1]; cpz = points[bA0*3+2];
    }

    for (int it = 0; it < 8; it++){
        const float ppx = cpx, ppy = cpy, ppz = cpz;   // snapshot current
        {   // prefetch next (clamped; last iter reloads tile 7 harmlessly)
            const int itn = it < 7 ? it + 1 : 7;
            const int bAn = (half*8 + itn)*64 + wv*16 + l16;
            cpx = points[bAn*3+0]; cpy = points[bAn*3+1]; cpz = points[bAn*3+2];
        }
        const float rx = pax - ppx;
        const float ry = pay - ppy;
        const float rz = paz - ppz;
        const float ss = rx*rx + ry*ry + rz*rz;
        const float dij = sqrtf(ss);
        const float inv = 1.0f / sqrtf(fmaxf(ss, 1e-8f));
        const float ux = rx*inv, uy = ry*inv, uz = rz*inv;  // ==0 on diagonal
        upx += ux; upy += uy; upz += uz;                    // 4x overcount, /4 later

        const bf16x8 afrag = make_afrag(dij, q);

        float uxr[4], uyr[4], uzr[4];
        #pragma unroll
        for (int r4 = 0; r4 < 4; r4++){
            const int sl = q*4 + r4;
            uxr[r4] = __shfl(ux, sl, 16);
            uyr[r4] = __shfl(uy, sl, 16);
            uzr[r4] = __shfl(uz, sl, 16);
        }

        #pragma unroll
        for (int nt = 0; nt < 2; nt++){
            f32x4 c = {b1v[0][nt], b1v[0][nt], b1v[0][nt], b1v[0][nt]};
            c = mfma16(afrag, w1hi[0][nt], c);
            c = mfma16(afrag, w1lo[0][nt], c);
            s0a[nt] += fmaxf(c[0],0.f)+fmaxf(c[1],0.f)+fmaxf(c[2],0.f)+fmaxf(c[3],0.f);
        }
        #pragma unroll
        for (int nt = 0; nt < 2; nt++){
            f32x4 c = {b1v[1][nt], b1v[1][nt], b1v[1][nt], b1v[1][nt]};
            c = mfma16(afrag, w1hi[1][nt], c);
            c = mfma16(afrag, w1lo[1][nt], c);
            #pragma unroll
            for (int r4 = 0; r4 < 4; r4++){
                const float h = fmaxf(c[r4], 0.f);
                T[nt][0] = fmaf(h, uxr[r4], T[nt][0]);
                T[nt][1] = fmaf(h, uyr[r4], T[nt][1]);
                T[nt][2] = fmaf(h, uzr[r4], T[nt][2]);
            }
        }
    }

    #pragma unroll
    for (int nt = 0; nt < 2; nt++){
        s0a[nt] += __shfl_down(s0a[nt], 32, 64);
        s0a[nt] += __shfl_down(s0a[nt], 16, 64);
        #pragma unroll
        for (int i = 0; i < 3; i++){
            T[nt][i] += __shfl_down(T[nt][i], 32, 64);
            T[nt][i] += __shfl_down(T[nt][i], 16, 64);
        }
    }
    #pragma unroll
    for (int off = 32; off > 0; off >>= 1){
        upx += __shfl_down(upx, off, 64);
        upy += __shfl_down(upy, off, 64);
        upz += __shfl_down(upz, off, 64);
    }
    if (lane < 16){
        sS0[wv][lane]      = s0a[0];
        sS0[wv][16 + lane] = s0a[1];
        #pragma unroll
        for (int i = 0; i < 3; i++){
            sT[wv][lane][i]      = T[0][i];
            sT[wv][16 + lane][i] = T[1][i];
        }
    }
    if (lane == 0){ sUp[wv][0] = upx; sUp[wv][1] = upy; sUp[wv][2] = upz; }
    __syncthreads();
    if (tid == 0){
        float o0 = 0.f;
        for (int j = 0; j < R; j++){
            const float S = sS0[0][j] + sS0[1][j] + sS0[2][j] + sS0[3][j];
            o0 = fmaf(S, W2[j], o0);
        }
        out0h[half*NP + a] = o0 + (float)(NP/2) * B2[0];
        for (int i = 0; i < 3; i++){
            float t = 0.f;
            for (int j = 0; j < R; j++){
                const float Tj = sT[0][j][i] + sT[1][j][i] + sT[2][j][i] + sT[3][j][i];
                t = fmaf(Tj, W2[R + j], t);
            }
            const float Ui = 0.25f * (sUp[0][i] + sUp[1][i] + sUp[2][i] + sUp[3][i]);
            out1h[(half*NP + a)*3 + i] = t + B2[1] * Ui;
        }
    }
}

// ---------------------------------------------------------------------------
// Per-point layer-1 features (sums split-K halves). x0g[b][f]; x1s SoA planes.
// ---------------------------------------------------------------------------
__global__ __launch_bounds__(256) void k_point1(
    const float* __restrict__ out0h, const float* __restrict__ out1h,
    const float* __restrict__ si0_w, const float* __restrict__ si0_b,
    const float* __restrict__ si1_w, const float* __restrict__ nl_b,
    float* __restrict__ x0g, float* __restrict__ x1s)
{
    const int b = blockIdx.x*256 + threadIdx.x;
    if (b >= NP) return;
    const float o0 = out0h[b] + out0h[NP + b];
    const float o1x = out1h[b*3+0] + out1h[(NP+b)*3+0];
    const float o1y = out1h[b*3+1] + out1h[(NP+b)*3+1];
    const float o1z = out1h[b*3+2] + out1h[(NP+b)*3+2];
    #pragma unroll
    for (int g = 0; g < C; g++){
        x0g[b*C+g] = eluf(fmaf(o0, si0_w[g], si0_b[g]));
        const float w = si1_w[g];
        const float tx = o1x*w, ty = o1y*w, tz = o1z*w;
        const float n = sqrtf(fmaxf(tx*tx + ty*ty + tz*tz, 1e-8f));
        const float sc = eluf(n + nl_b[g]) / n;
        x1s[0*NP*C + b*C+g] = tx*sc;
        x1s[1*NP*C + b*C+g] = ty*sc;
        x1s[2*NP*C + b*C+g] = tz*sc;
    }
}

// ---------------------------------------------------------------------------
// Layer 2 (MFMA, barrier-free, split-K x2, SW-pipelined global loads).
// Live filters 0 (0x0->0) and 2 (1x1->0) only.
// ---------------------------------------------------------------------------
__global__ __launch_bounds__(256) void k_layer2(
    const float* __restrict__ points,
    const float* __restrict__ W1, const float* __restrict__ B1,
    const float* __restrict__ W2, const float* __restrict__ B2,
    const float* __restrict__ x0g, const float* __restrict__ x1s,
    float* __restrict__ c00h, float* __restrict__ c10h)
{
    __shared__ __align__(16) short sH[4][2][16*40];   // [wave][filter][row*40]
    __shared__ float sRed[4][2][16];

    const int tid  = threadIdx.x;
    const int lane = tid & 63;
    const int wv   = tid >> 6;
    const int l16  = lane & 15;
    const int q    = lane >> 4;
    const int a    = blockIdx.x >> 1;
    const int half = blockIdx.x & 1;
    const float pax = points[a*3+0], pay = points[a*3+1], paz = points[a*3+2];

    bf16x8 w1hi[2][2], w1lo[2][2], w2hi[2], w2lo[2];
    float  b1v[2][2], b2v[2];
    #pragma unroll
    for (int fi = 0; fi < 2; fi++){
        const int fx = (fi == 0) ? 0 : 2;
        #pragma unroll
        for (int nt = 0; nt < 2; nt++){
            load_bfrag<R>(W1 + fx*R*R, q, 2*l16 + nt, w1hi[fi][nt], w1lo[fi][nt]);
            b1v[fi][nt] = B1[fx*R + 2*l16 + nt];
        }
        load_bfrag<C>(W2 + fx*R*C, q, l16, w2hi[fi], w2lo[fi]);
        b2v[fi] = B2[fx*C + l16];
    }

    float acc0 = 0.f, acc1 = 0.f;
    short* sH0 = sH[wv][0];
    short* sH1 = sH[wv][1];

    // prologue prefetch (tile it=0)
    float cpx, cpy, cpz;
    float ax0[4], a1x[4], a1y[4], a1z[4];
    {
        const int bA0 = (half*8)*64 + wv*16 + l16;
        cpx = points[bA0*3+0]; cpy = points[bA0*3+1]; cpz = points[bA0*3+2];
        const int rb0 = ((half*8)*64 + wv*16 + q*4)*C + l16;
        #pragma unroll
        for (int r4 = 0; r4 < 4; r4++){
            ax0[r4] = x0g[rb0 + r4*C];
            a1x[r4] = x1s[0*NP*C + rb0 + r4*C];
            a1y[r4] = x1s[1*NP*C + rb0 + r4*C];
            a1z[r4] = x1s[2*NP*C + rb0 + r4*C];
        }
    }

    for (int it = 0; it < 8; it++){
        // snapshot current tile's prefetched data
        const float ppx = cpx, ppy = cpy, ppz = cpz;
        float x0v[4], v1x[4], v1y[4], v1z[4];
        #pragma unroll
        for (int r4 = 0; r4 < 4; r4++){
            x0v[r4] = ax0[r4]; v1x[r4] = a1x[r4]; v1y[r4] = a1y[r4]; v1z[r4] = a1z[r4];
        }
        {   // prefetch next tile (issued BEFORE the lgkm barrier; in flight
            // across the whole LDS round trip; consumed next iteration)
            const int itn = it < 7 ? it + 1 : 7;
            const int bAn = (half*8 + itn)*64 + wv*16 + l16;
            cpx = points[bAn*3+0]; cpy = points[bAn*3+1]; cpz = points[bAn*3+2];
            const int rbn = ((half*8 + itn)*64 + wv*16 + q*4)*C + l16;
            #pragma unroll
            for (int r4 = 0; r4 < 4; r4++){
                ax0[r4] = x0g[rbn + r4*C];
                a1x[r4] = x1s[0*NP*C + rbn + r4*C];
                a1y[r4] = x1s[1*NP*C + rbn + r4*C];
                a1z[r4] = x1s[2*NP*C + rbn + r4*C];
            }
        }

        const float rx = pax - ppx;
        const float ry = pay - ppy;
        const float rz = paz - ppz;
        const float ss = rx*rx + ry*ry + rz*rz;
        const float dij = sqrtf(ss);
        const float inv = 1.0f / sqrtf(fmaxf(ss, 1e-8f));
        const float ux = rx*inv, uy = ry*inv, uz = rz*inv;  // ==0 on diagonal

        float uxr[4], uyr[4], uzr[4];
        #pragma unroll
        for (int r4 = 0; r4 < 4; r4++){
            const int sl = q*4 + r4;
            uxr[r4] = __shfl(ux, sl, 16);
            uyr[r4] = __shfl(uy, sl, 16);
            uzr[r4] = __shfl(uz, sl, 16);
        }
        float udv[4];
        #pragma unroll
        for (int r4 = 0; r4 < 4; r4++)
            udv[r4] = uxr[r4]*v1x[r4] + uyr[r4]*v1y[r4] + uzr[r4]*v1z[r4];

        const bf16x8 afrag = make_afrag(dij, q);

        // GEMM1 both filters -> packed bf16 H into wave-private LDS
        #pragma unroll
        for (int fi = 0; fi < 2; fi++){
            f32x4 c0 = {b1v[fi][0], b1v[fi][0], b1v[fi][0], b1v[fi][0]};
            c0 = mfma16(afrag, w1hi[fi][0], c0);
            c0 = mfma16(afrag, w1lo[fi][0], c0);
            f32x4 c1 = {b1v[fi][1], b1v[fi][1], b1v[fi][1], b1v[fi][1]};
            c1 = mfma16(afrag, w1hi[fi][1], c1);
            c1 = mfma16(afrag, w1lo[fi][1], c1);
            short* sHf = (fi == 0) ? sH0 : sH1;
            #pragma unroll
            for (int r4 = 0; r4 < 4; r4++){
                const unsigned p = pack2bf(fmaxf(c0[r4], 0.f), fmaxf(c1[r4], 0.f));
                *(unsigned*)&sHf[(q*4+r4)*40 + 2*l16] = p;   // j=2l16 / 2l16+1
            }
        }
        asm volatile("s_waitcnt lgkmcnt(0)" ::: "memory");   // wave-internal transpose
        #pragma unroll
        for (int fi = 0; fi < 2; fi++){
            const short* sHf = (fi == 0) ? sH0 : sH1;
            const bf16x8 hf = *(const bf16x8*)(sHf + l16*40 + q*8);
            f32x4 d = {b2v[fi], b2v[fi], b2v[fi], b2v[fi]};   // bias pre-seeded
            d = mfma16(hf, w2hi[fi], d);
            d = mfma16(hf, w2lo[fi], d);
            #pragma unroll
            for (int r4 = 0; r4 < 4; r4++){
                if (fi == 0) acc0 = fmaf(d[r4], x0v[r4], acc0);
                else         acc1 = fmaf(d[r4], udv[r4], acc1);
            }
        }
    }

    acc0 += __shfl_down(acc0, 32, 64); acc0 += __shfl_down(acc0, 16, 64);
    acc1 += __shfl_down(acc1, 32, 64); acc1 += __shfl_down(acc1, 16, 64);
    if (lane < 16){ sRed[wv][0][lane] = acc0; sRed[wv][1][lane] = acc1; }
    __syncthreads();
    if (tid < 16)
        c00h[half*NP*C + a*C + tid] =
            sRed[0][0][tid] + sRed[1][0][tid] + sRed[2][0][tid] + sRed[3][0][tid];
    else if (tid < 32){
        const int f = tid - 16;
        c10h[half*NP*C + a*C + f] =
            sRed[0][1][f] + sRed[1][1][f] + sRed[2][1][f] + sRed[3][1][f];
    }
}

// ---------------------------------------------------------------------------
// Fused readout: single block. Sum split-K halves -> layer-2 degree-0 elu
// features -> mean pool -> final FC. 256 threads x 4 points each.
// ---------------------------------------------------------------------------
__global__ __launch_bounds__(256) void k_readout(
    const float* __restrict__ c00h, const float* __restrict__ c10h,
    const float* __restrict__ si0_w, const float* __restrict__ si0_b,
    const float* __restrict__ fc_w, const float* __restrict__ fc_b,
    float* __restrict__ out)
{
    __shared__ float sred[4*C];
    __shared__ float sG[C];
    const int tid = threadIdx.x;
    float xs[C] = {};
    #pragma unroll
    for (int p = 0; p < 4; p++){
        const int aa = p*256 + tid;
        float v00[C], v10[C];
        #pragma unroll
        for (int f = 0; f < C; f++){
            v00[f] = c00h[aa*C+f] + c00h[NP*C + aa*C+f];
            v10[f] = c10h[aa*C+f] + c10h[NP*C + aa*C+f];
        }
        #pragma unroll
        for (int g = 0; g < C; g++){
            float s = si0_b[g];
            #pragma unroll
            for (int f = 0; f < C; f++) s = fmaf(v00[f], si0_w[g*2*C + f], s);
            #pragma unroll
            for (int f = 0; f < C; f++) s = fmaf(v10[f], si0_w[g*2*C + C + f], s);
            xs[g] += eluf(s);
        }
    }
    #pragma unroll
    for (int off = 32; off > 0; off >>= 1){
        #pragma unroll
        for (int g = 0; g < C; g++) xs[g] += __shfl_down(xs[g], off, 64);
    }
    const int lane = tid & 63, wv = tid >> 6;
    if (lane == 0){
        #pragma unroll
        for (int g = 0; g < C; g++) sred[wv*C + g] = xs[g];
    }
    __syncthreads();
    if (tid < C)
        sG[tid] = (sred[tid] + sred[C + tid] + sred[2*C + tid] + sred[3*C + tid])
                  * (1.0f / (float)NP);
    __syncthreads();
    if (tid < 8){
        float s = fc_b[tid];
        #pragma unroll
        for (int g = 0; g < C; g++) s = fmaf(sG[g], fc_w[g*8 + tid], s);
        out[tid] = s;
    }
}

extern "C" void kernel_launch(void* const* d_in, const int* in_sizes, int n_in,
                              void* d_out, int out_size, void* d_ws, size_t ws_size,
                              hipStream_t stream)
{
    (void)in_sizes; (void)n_in; (void)out_size; (void)ws_size;
    const float* points   = (const float*)d_in[0];
    const float* l1_W1    = (const float*)d_in[1];
    const float* l1_B1    = (const float*)d_in[2];
    const float* l1_W2    = (const float*)d_in[3];
    const float* l1_B2    = (const float*)d_in[4];
    const float* l1_si0_w = (const float*)d_in[5];
    const float* l1_si0_b = (const float*)d_in[6];
    const float* l1_si1_w = (const float*)d_in[7];
    const float* l1_nl_b  = (const float*)d_in[8];
    const float* l2_W1    = (const float*)d_in[9];
    const float* l2_B1    = (const float*)d_in[10];
    const float* l2_W2    = (const float*)d_in[11];
    const float* l2_B2    = (const float*)d_in[12];
    const float* l2_si0_w = (const float*)d_in[13];
    const float* l2_si0_b = (const float*)d_in[14];
    // d_in[15] l2_si1_w, d_in[16] l2_nl_b: dead code in the reference readout
    const float* fc_w     = (const float*)d_in[17];
    const float* fc_b     = (const float*)d_in[18];

    float* ws    = (float*)d_ws;
    float* out0h = ws;                    // 2*NP
    float* out1h = out0h + 2*NP;          // 2*NP*3
    float* x0g   = out1h + 2*NP*3;        // NP*C
    float* x1s   = x0g + NP*C;            // 3*NP*C (SoA planes)
    float* c00h  = x1s + 3*NP*C;          // 2*NP*C
    float* c10h  = c00h + 2*NP*C;         // 2*NP*C

    k_layer1<<<2*NP, 256, 0, stream>>>(points, l1_W1, l1_B1, l1_W2, l1_B2, out0h, out1h);
    k_point1<<<NP/256, 256, 0, stream>>>(out0h, out1h, l1_si0_w, l1_si0_b, l1_si1_w, l1_nl_b, x0g, x1s);
    k_layer2<<<2*NP, 256, 0, stream>>>(points, l2_W1, l2_B1, l2_W2, l2_B2, x0g, x1s, c00h, c10h);
    k_readout<<<1, 256, 0, stream>>>(c00h, c10h, l2_si0_w, l2_si0_b, fc_w, fc_b, (float*)d_out);
}

// Round 8
// 184.633 us; speedup vs baseline: 1.0706x; 1.0706x over previous
//
#include <hip/hip_runtime.h>
#include <math.h>

#define NP 1024
#define R 32
#define C 16
#define GAMMA (32.0f/3.5f)
#define DC (3.5f/31.0f)

// radial-table parameters: F_f(dij) tabulated on [0, 5.1175], linear interp.
// Beyond 5.12 every rbf < e^-23 -> F constant -> clamped lerp is exact.
#define TT 2048
#define DTT 0.0025f
#define INV_DTT 400.0f
#define TCLAMP 2046.999f

__device__ __forceinline__ float eluf(float x){ return x > 0.f ? x : expm1f(x); }

// ---------------------------------------------------------------------------
// k_tab: build radial tables (exact fp32 MLP per grid point) + pack points
// into float4. Blocks 0..31: tables (fi = bx>>3: 0,1 = layer1 filters 0,1;
// 2,3 = layer2 filters 0,2 — the only live ones; layer-2 degree-1 outputs are
// dead code in the reference). Blocks 32..35: pts4 pack.
// tab1[t] = float2(rad_l1f0, rad_l1f1); tab2[t*16+f] = float2(rad_l2f0, rad_l2f2)
// ---------------------------------------------------------------------------
__global__ __launch_bounds__(256) void k_tab(
    const float* __restrict__ points,
    const float* __restrict__ l1W1, const float* __restrict__ l1B1,
    const float* __restrict__ l1W2, const float* __restrict__ l1B2,
    const float* __restrict__ l2W1, const float* __restrict__ l2B1,
    const float* __restrict__ l2W2, const float* __restrict__ l2B2,
    float* __restrict__ tab1, float* __restrict__ tab2, float* __restrict__ pts4)
{
    const int bx = blockIdx.x;
    const int tid = threadIdx.x;
    if (bx >= 32){
        const int b = (bx - 32)*256 + tid;
        pts4[b*4+0] = points[b*3+0];
        pts4[b*4+1] = points[b*3+1];
        pts4[b*4+2] = points[b*3+2];
        pts4[b*4+3] = 0.f;
        return;
    }
    const int fi = bx >> 3;
    const int t  = (bx & 7)*256 + tid;
    const float dij = (float)t * DTT;

    float rbf[R];
    #pragma unroll
    for (int k = 0; k < R; k++){
        const float d = dij - (float)k*DC;
        rbf[k] = expf(-GAMMA*d*d);
    }
    const int lf = (fi < 2) ? fi : ((fi == 2) ? 0 : 2);
    const float* W1 = (fi < 2 ? l1W1 : l2W1) + lf*R*R;
    const float* B1 = (fi < 2 ? l1B1 : l2B1) + lf*R;
    float h[R];
    for (int j = 0; j < R; j++){
        float s = B1[j];
        #pragma unroll 8
        for (int k = 0; k < R; k++) s = fmaf(rbf[k], W1[k*R + j], s);
        h[j] = fmaxf(s, 0.f);
    }
    if (fi < 2){
        float r = l1B2[lf];
        #pragma unroll 8
        for (int j = 0; j < R; j++) r = fmaf(h[j], l1W2[lf*R + j], r);
        tab1[t*2 + fi] = r;
    } else {
        const int c = (fi == 2) ? 0 : 1;
        for (int f = 0; f < C; f++){
            float r = l2B2[lf*C + f];
            #pragma unroll 8
            for (int j = 0; j < R; j++) r = fmaf(h[j], l2W2[(lf*R + j)*C + f], r);
            tab2[(t*C + f)*2 + c] = r;
        }
    }
}

// ---------------------------------------------------------------------------
// k_l1: layer-1 pair pass via table lookup + fused nonlinearity.
// out0[a] = sum_b F0(dij); out1[a,i] = sum_b F1(dij)*u_i (u=0 on diagonal
// makes the mask implicit). Tail computes x0/x1 nonlinearity and writes
// xq[a*16+g] = float4(x0, x1x, x1y, x1z).
// ---------------------------------------------------------------------------
__global__ __launch_bounds__(256) void k_l1(
    const float* __restrict__ pts4, const float* __restrict__ tab1,
    const float* __restrict__ si0_w, const float* __restrict__ si0_b,
    const float* __restrict__ si1_w, const float* __restrict__ nl_b,
    float* __restrict__ xq)
{
    __shared__ float sRed[4][4];
    __shared__ float sO[4];
    const int tid = threadIdx.x;
    const int a = blockIdx.x;
    const float4 pa = ((const float4*)pts4)[a];
    float acc0 = 0.f, ax = 0.f, ay = 0.f, az = 0.f;
    #pragma unroll
    for (int k = 0; k < 4; k++){
        const int b = tid + 256*k;
        const float4 pb = ((const float4*)pts4)[b];
        const float rx = pa.x - pb.x, ry = pa.y - pb.y, rz = pa.z - pb.z;
        const float ss = rx*rx + ry*ry + rz*rz;
        const float dij = sqrtf(ss);
        const float inv = 1.0f / sqrtf(fmaxf(ss, 1e-8f));
        const float tt = fminf(dij * INV_DTT, TCLAMP);
        const int   i  = (int)tt;
        const float w  = tt - (float)i;
        const float2 t0 = ((const float2*)tab1)[i];
        const float2 t1 = ((const float2*)tab1)[i+1];
        const float r00 = fmaf(w, t1.x - t0.x, t0.x);
        const float r01 = fmaf(w, t1.y - t0.y, t0.y);
        acc0 += r00;
        ax = fmaf(r01, rx*inv, ax);
        ay = fmaf(r01, ry*inv, ay);
        az = fmaf(r01, rz*inv, az);
    }
    #pragma unroll
    for (int off = 32; off > 0; off >>= 1){
        acc0 += __shfl_down(acc0, off, 64);
        ax   += __shfl_down(ax,   off, 64);
        ay   += __shfl_down(ay,   off, 64);
        az   += __shfl_down(az,   off, 64);
    }
    const int lane = tid & 63, wv = tid >> 6;
    if (lane == 0){ sRed[wv][0]=acc0; sRed[wv][1]=ax; sRed[wv][2]=ay; sRed[wv][3]=az; }
    __syncthreads();
    if (tid < 4) sO[tid] = sRed[0][tid] + sRed[1][tid] + sRed[2][tid] + sRed[3][tid];
    __syncthreads();
    if (tid < C){
        const int g = tid;
        const float x0 = eluf(fmaf(sO[0], si0_w[g], si0_b[g]));
        const float wg = si1_w[g];
        const float tx = sO[1]*wg, ty = sO[2]*wg, tz = sO[3]*wg;
        const float n = sqrtf(fmaxf(tx*tx + ty*ty + tz*tz, 1e-8f));
        const float sc = eluf(n + nl_b[g]) / n;
        ((float4*)xq)[a*C + g] = make_float4(x0, tx*sc, ty*sc, tz*sc);
    }
}

// ---------------------------------------------------------------------------
// k_l2: layer-2 pair pass via table lookup. Thread (bg=tid>>4, f=tid&15);
// 64 b's per thread. Table reads are 128B-contiguous per 16-lane b-group.
// c00[a,f] = sum_b F2_0(dij,f)*x0[b,f]
// c10[a,f] = sum_b F2_2(dij,f)*dot(u, x1[b,f,:])   (u=0 on diagonal)
// ---------------------------------------------------------------------------
__global__ __launch_bounds__(256) void k_l2(
    const float* __restrict__ pts4, const float* __restrict__ tab2,
    const float* __restrict__ xq,
    float* __restrict__ c00, float* __restrict__ c10)
{
    __shared__ float sA[16][17];
    __shared__ float sB[16][17];
    const int tid = threadIdx.x;
    const int f  = tid & 15;
    const int bg = tid >> 4;
    const int a = blockIdx.x;
    const float4 pa = ((const float4*)pts4)[a];
    float acc0 = 0.f, acc1 = 0.f;
    #pragma unroll 4
    for (int k = 0; k < 64; k++){
        const int b = bg*64 + k;
        const float4 pb = ((const float4*)pts4)[b];
        const float rx = pa.x - pb.x, ry = pa.y - pb.y, rz = pa.z - pb.z;
        const float ss = rx*rx + ry*ry + rz*rz;
        const float dij = sqrtf(ss);
        const float inv = 1.0f / sqrtf(fmaxf(ss, 1e-8f));
        const float tt = fminf(dij * INV_DTT, TCLAMP);
        const int   i  = (int)tt;
        const float w  = tt - (float)i;
        const float2 t0 = ((const float2*)tab2)[i*C + f];
        const float2 t1 = ((const float2*)tab2)[(i+1)*C + f];
        const float r0 = fmaf(w, t1.x - t0.x, t0.x);
        const float r2 = fmaf(w, t1.y - t0.y, t0.y);
        const float4 xv = ((const float4*)xq)[b*C + f];
        const float ud = (rx*xv.y + ry*xv.z + rz*xv.w) * inv;   // u . x1
        acc0 = fmaf(r0, xv.x, acc0);
        acc1 = fmaf(r2, ud, acc1);
    }
    sA[bg][f] = acc0;
    sB[bg][f] = acc1;
    __syncthreads();
    if (tid < C){
        float s = 0.f;
        #pragma unroll
        for (int g = 0; g < 16; g++) s += sA[g][tid];
        c00[a*C + tid] = s;
    } else if (tid < 2*C){
        const int ff = tid - C;
        float s = 0.f;
        #pragma unroll
        for (int g = 0; g < 16; g++) s += sB[g][ff];
        c10[a*C + ff] = s;
    }
}

// ---------------------------------------------------------------------------
// Fused readout: single block. Layer-2 degree-0 elu features -> mean pool ->
// final FC. 256 threads x 4 points each.
// ---------------------------------------------------------------------------
__global__ __launch_bounds__(256) void k_readout(
    const float* __restrict__ c00, const float* __restrict__ c10,
    const float* __restrict__ si0_w, const float* __restrict__ si0_b,
    const float* __restrict__ fc_w, const float* __restrict__ fc_b,
    float* __restrict__ out)
{
    __shared__ float sred[4*C];
    __shared__ float sG[C];
    const int tid = threadIdx.x;
    float xs[C] = {};
    #pragma unroll
    for (int p = 0; p < 4; p++){
        const int aa = p*256 + tid;
        float v00[C], v10[C];
        #pragma unroll
        for (int f = 0; f < C; f++){
            v00[f] = c00[aa*C+f];
            v10[f] = c10[aa*C+f];
        }
        #pragma unroll
        for (int g = 0; g < C; g++){
            float s = si0_b[g];
            #pragma unroll
            for (int f = 0; f < C; f++) s = fmaf(v00[f], si0_w[g*2*C + f], s);
            #pragma unroll
            for (int f = 0; f < C; f++) s = fmaf(v10[f], si0_w[g*2*C + C + f], s);
            xs[g] += eluf(s);
        }
    }
    #pragma unroll
    for (int off = 32; off > 0; off >>= 1){
        #pragma unroll
        for (int g = 0; g < C; g++) xs[g] += __shfl_down(xs[g], off, 64);
    }
    const int lane = tid & 63, wv = tid >> 6;
    if (lane == 0){
        #pragma unroll
        for (int g = 0; g < C; g++) sred[wv*C + g] = xs[g];
    }
    __syncthreads();
    if (tid < C)
        sG[tid] = (sred[tid] + sred[C + tid] + sred[2*C + tid] + sred[3*C + tid])
                  * (1.0f / (float)NP);
    __syncthreads();
    if (tid < 8){
        float s = fc_b[tid];
        #pragma unroll
        for (int g = 0; g < C; g++) s = fmaf(sG[g], fc_w[g*8 + tid], s);
        out[tid] = s;
    }
}

extern "C" void kernel_launch(void* const* d_in, const int* in_sizes, int n_in,
                              void* d_out, int out_size, void* d_ws, size_t ws_size,
                              hipStream_t stream)
{
    (void)in_sizes; (void)n_in; (void)out_size; (void)ws_size;
    const float* points   = (const float*)d_in[0];
    const float* l1_W1    = (const float*)d_in[1];
    const float* l1_B1    = (const float*)d_in[2];
    const float* l1_W2    = (const float*)d_in[3];
    const float* l1_B2    = (const float*)d_in[4];
    const float* l1_si0_w = (const float*)d_in[5];
    const float* l1_si0_b = (const float*)d_in[6];
    const float* l1_si1_w = (const float*)d_in[7];
    const float* l1_nl_b  = (const float*)d_in[8];
    const float* l2_W1    = (const float*)d_in[9];
    const float* l2_B1    = (const float*)d_in[10];
    const float* l2_W2    = (const float*)d_in[11];
    const float* l2_B2    = (const float*)d_in[12];
    const float* l2_si0_w = (const float*)d_in[13];
    const float* l2_si0_b = (const float*)d_in[14];
    // d_in[15] l2_si1_w, d_in[16] l2_nl_b: dead code in the reference readout
    const float* fc_w     = (const float*)d_in[17];
    const float* fc_b     = (const float*)d_in[18];

    float* ws   = (float*)d_ws;
    float* tab1 = ws;                 // 2*TT       (16B-aligned offsets throughout)
    float* tab2 = tab1 + 2*TT;        // 32*TT
    float* pts4 = tab2 + 32*TT;       // 4*NP
    float* xq   = pts4 + 4*NP;        // 4*NP*C
    float* c00  = xq + 4*NP*C;        // NP*C
    float* c10  = c00 + NP*C;         // NP*C

    k_tab<<<36, 256, 0, stream>>>(points, l1_W1, l1_B1, l1_W2, l1_B2,
                                  l2_W1, l2_B1, l2_W2, l2_B2, tab1, tab2, pts4);
    k_l1<<<NP, 256, 0, stream>>>(pts4, tab1, l1_si0_w, l1_si0_b, l1_si1_w, l1_nl_b, xq);
    k_l2<<<NP, 256, 0, stream>>>(pts4, tab2, xq, c00, c10);
    k_readout<<<1, 256, 0, stream>>>(c00, c10, l2_si0_w, l2_si0_b, fc_w, fc_b, (float*)d_out);
}

// Round 9
// 182.560 us; speedup vs baseline: 1.0828x; 1.0114x over previous
//
#include <hip/hip_runtime.h>
#include <math.h>

#define NP 1024
#define R 32
#define C 16
#define GAMMA (32.0f/3.5f)
#define DC (3.5f/31.0f)

// radial tables: F_f(dij) on [0, 5.1175] grid, linear interp (clamped; all
// RBFs < e^-23 beyond the grid so F is constant there).
#define TT 2048
#define DTT 0.0025f
#define INV_DTT 400.0f
#define TCLAMP 2046.999f

#define SGIDX(b) ((b) + ((b) >> 4))   // LDS pad: break 4-way b128 conflicts

__device__ __forceinline__ float eluf(float x){ return x > 0.f ? x : expm1f(x); }
__device__ __forceinline__ float rsqf(float x){ return __builtin_amdgcn_rsqf(x); }

// ---------------------------------------------------------------------------
// k_tab: build PACKED lerp tables (entry i holds F at i and i+1 -> single
// gather in the pair kernels), pack pts4, zero the pooled accumulators.
//   tab1d[t] = float4(F1_0(t), F1_1(t), F1_0(t+1), F1_1(t+1))
//   tab2d[t*16+f] = float4(F2_0(t,f), F2_2(t,f), F2_0(t+1,f), F2_2(t+1,f))
// Live filters only: layer1 {0,1}; layer2 {0,2} (layer-2 degree-1 outputs are
// dead code in the reference readout).
// ---------------------------------------------------------------------------
__global__ __launch_bounds__(256) void k_tab(
    const float* __restrict__ points,
    const float* __restrict__ l1W1, const float* __restrict__ l1B1,
    const float* __restrict__ l1W2, const float* __restrict__ l1B2,
    const float* __restrict__ l2W1, const float* __restrict__ l2B1,
    const float* __restrict__ l2W2, const float* __restrict__ l2B2,
    float* __restrict__ tab1d, float* __restrict__ tab2d,
    float* __restrict__ pts4, float* __restrict__ accz)
{
    const int bx = blockIdx.x;
    const int tid = threadIdx.x;
    if (bx == 36){
        if (tid < 9) accz[tid] = 0.f;          // 8 pooled floats + counter
        return;
    }
    if (bx >= 32){
        const int b = (bx - 32)*256 + tid;
        pts4[b*4+0] = points[b*3+0];
        pts4[b*4+1] = points[b*3+1];
        pts4[b*4+2] = points[b*3+2];
        pts4[b*4+3] = 0.f;
        return;
    }
    const int fi = bx >> 3;                     // 0,1: layer1; 2,3: layer2
    const int t  = (bx & 7)*256 + tid;
    const float dij = (float)t * DTT;

    float rbf[R];
    #pragma unroll
    for (int k = 0; k < R; k++){
        const float d = dij - (float)k*DC;
        rbf[k] = expf(-GAMMA*d*d);
    }
    const int lf = (fi < 2) ? fi : ((fi == 2) ? 0 : 2);
    const float* W1 = (fi < 2 ? l1W1 : l2W1) + lf*R*R;
    const float* B1 = (fi < 2 ? l1B1 : l2B1) + lf*R;
    float h[R];
    for (int j = 0; j < R; j++){
        float s = B1[j];
        #pragma unroll 8
        for (int k = 0; k < R; k++) s = fmaf(rbf[k], W1[k*R + j], s);
        h[j] = fmaxf(s, 0.f);
    }
    if (fi < 2){
        float r = l1B2[lf];
        #pragma unroll 8
        for (int j = 0; j < R; j++) r = fmaf(h[j], l1W2[lf*R + j], r);
        tab1d[t*4 + fi] = r;                    // .x/.y at node t
        if (t >= 1) tab1d[(t-1)*4 + 2 + fi] = r; // .z/.w at node t-1
    } else {
        const int c = fi - 2;
        for (int f = 0; f < C; f++){
            float r = l2B2[lf*C + f];
            #pragma unroll 8
            for (int j = 0; j < R; j++) r = fmaf(h[j], l2W2[(lf*R + j)*C + f], r);
            tab2d[(t*C + f)*4 + c] = r;
            if (t >= 1) tab2d[((t-1)*C + f)*4 + 2 + c] = r;
        }
    }
}

// ---------------------------------------------------------------------------
// k_l1: layer-1 pair pass, single packed gather per pair, rsq geometry.
// out0[a] = sum_b F0; out1[a,i] = sum_b F1*u_i (u==0 on diagonal). Tail does
// the nonlinearity: xq[a*16+g] = float4(x0, x1x, x1y, x1z).
// ---------------------------------------------------------------------------
__global__ __launch_bounds__(256) void k_l1(
    const float* __restrict__ pts4, const float* __restrict__ tab1d,
    const float* __restrict__ si0_w, const float* __restrict__ si0_b,
    const float* __restrict__ si1_w, const float* __restrict__ nl_b,
    float* __restrict__ xq)
{
    __shared__ float sRed[4][4];
    __shared__ float sO[4];
    const int tid = threadIdx.x;
    const int a = blockIdx.x;
    const float4 pa = ((const float4*)pts4)[a];
    float acc0 = 0.f, ax = 0.f, ay = 0.f, az = 0.f;
    #pragma unroll
    for (int k = 0; k < 4; k++){
        const int b = tid + 256*k;
        const float4 pb = ((const float4*)pts4)[b];
        const float rx = pa.x - pb.x, ry = pa.y - pb.y, rz = pa.z - pb.z;
        const float ss = rx*rx + ry*ry + rz*rz;
        const float inv = rsqf(fmaxf(ss, 1e-8f));
        const float dij = ss * inv;                  // exact 0 on diagonal
        const float tt = fminf(dij * INV_DTT, TCLAMP);
        const int   i  = (int)tt;
        const float w  = tt - (float)i;
        const float4 t4 = ((const float4*)tab1d)[i]; // one gather
        const float r00 = fmaf(w, t4.z - t4.x, t4.x);
        const float r01 = fmaf(w, t4.w - t4.y, t4.y) * inv;
        acc0 += r00;
        ax = fmaf(r01, rx, ax);
        ay = fmaf(r01, ry, ay);
        az = fmaf(r01, rz, az);
    }
    #pragma unroll
    for (int off = 32; off > 0; off >>= 1){
        acc0 += __shfl_down(acc0, off, 64);
        ax   += __shfl_down(ax,   off, 64);
        ay   += __shfl_down(ay,   off, 64);
        az   += __shfl_down(az,   off, 64);
    }
    const int lane = tid & 63, wv = tid >> 6;
    if (lane == 0){ sRed[wv][0]=acc0; sRed[wv][1]=ax; sRed[wv][2]=ay; sRed[wv][3]=az; }
    __syncthreads();
    if (tid < 4) sO[tid] = sRed[0][tid] + sRed[1][tid] + sRed[2][tid] + sRed[3][tid];
    __syncthreads();
    if (tid < C){
        const int g = tid;
        const float x0 = eluf(fmaf(sO[0], si0_w[g], si0_b[g]));
        const float wg = si1_w[g];
        const float tx = sO[1]*wg, ty = sO[2]*wg, tz = sO[3]*wg;
        const float n = sqrtf(fmaxf(tx*tx + ty*ty + tz*tz, 1e-8f));
        const float sc = eluf(n + nl_b[g]) / n;
        ((float4*)xq)[a*C + g] = make_float4(x0, tx*sc, ty*sc, tz*sc);
    }
}

// ---------------------------------------------------------------------------
// k_l2: layer-2 pair pass + FUSED pooled readout.
// Phase 1: per-b geometry (tt, unit vector) once per block -> LDS.
// Phase 2: thread (bg=tid>>4, f=tid&15), 64 b's each; geometry via broadcast
// ds_read; one packed table load; coalesced xq load.
// Tail: c00/c10 -> elu features -> per-block FC contribution -> 8 global
// fp32 atomics; last block (device-scope counter) writes d_out.
// ---------------------------------------------------------------------------
__global__ __launch_bounds__(256) void k_l2(
    const float* __restrict__ pts4, const float* __restrict__ tab2d,
    const float* __restrict__ xq,
    const float* __restrict__ si0_w, const float* __restrict__ si0_b,
    const float* __restrict__ fc_w, const float* __restrict__ fc_b,
    float* __restrict__ acc, int* __restrict__ counter,
    float* __restrict__ out)
{
    __shared__ float4 sGeo[NP + NP/16];     // padded: SGIDX
    __shared__ float sC[16][17], sD[16][17];
    __shared__ float sCf[16], sDf[16], sX[16];
    const int tid = threadIdx.x;
    const int a = blockIdx.x;
    const float4 pa = ((const float4*)pts4)[a];

    // phase 1: geometry for all 1024 b's
    #pragma unroll
    for (int k = 0; k < 4; k++){
        const int b = tid + 256*k;
        const float4 pb = ((const float4*)pts4)[b];
        const float rx = pa.x - pb.x, ry = pa.y - pb.y, rz = pa.z - pb.z;
        const float ss = rx*rx + ry*ry + rz*rz;
        const float inv = rsqf(fmaxf(ss, 1e-8f));
        const float dij = ss * inv;                  // exact 0 on diagonal
        const float tt = fminf(dij * INV_DTT, TCLAMP);
        sGeo[SGIDX(b)] = make_float4(tt, rx*inv, ry*inv, rz*inv);
    }
    __syncthreads();

    // phase 2
    const int f  = tid & 15;
    const int bg = tid >> 4;
    float acc0 = 0.f, acc1 = 0.f;
    #pragma unroll 4
    for (int k = 0; k < 64; k++){
        const int b = bg*64 + k;
        const float4 g = sGeo[SGIDX(b)];             // broadcast in f-group
        const int   i = (int)g.x;
        const float w = g.x - (float)i;
        const float4 t4 = ((const float4*)tab2d)[i*C + f];  // 256B/group
        const float4 xv = ((const float4*)xq)[b*C + f];     // coalesced
        const float r0 = fmaf(w, t4.z - t4.x, t4.x);
        const float r2 = fmaf(w, t4.w - t4.y, t4.y);
        const float ud = g.y*xv.y + g.z*xv.z + g.w*xv.w;    // u . x1
        acc0 = fmaf(r0, xv.x, acc0);
        acc1 = fmaf(r2, ud, acc1);
    }
    sC[bg][f] = acc0;
    sD[bg][f] = acc1;
    __syncthreads();

    // tail: reduce over bg, nonlinearity, FC contribution, pool atomically
    if (tid < 16){
        float s = 0.f;
        #pragma unroll
        for (int g2 = 0; g2 < 16; g2++) s += sC[g2][tid];
        sCf[tid] = s;
    } else if (tid < 32){
        const int ff = tid - 16;
        float s = 0.f;
        #pragma unroll
        for (int g2 = 0; g2 < 16; g2++) s += sD[g2][ff];
        sDf[ff] = s;
    }
    __syncthreads();
    if (tid < 16){
        const int g2 = tid;
        float s = si0_b[g2];
        #pragma unroll
        for (int ff = 0; ff < C; ff++) s = fmaf(sCf[ff], si0_w[g2*2*C + ff], s);
        #pragma unroll
        for (int ff = 0; ff < C; ff++) s = fmaf(sDf[ff], si0_w[g2*2*C + C + ff], s);
        sX[g2] = eluf(s);
    }
    __syncthreads();
    if (tid < 8){
        float v = 0.f;
        #pragma unroll
        for (int g2 = 0; g2 < C; g2++) v = fmaf(sX[g2], fc_w[g2*8 + tid], v);
        atomicAdd(&acc[tid], v);                     // device-scope
    }
    __syncthreads();                                 // drains the atomics
    if (tid == 0){
        __threadfence();
        const int old = atomicAdd(counter, 1);
        if (old == (int)gridDim.x - 1){
            #pragma unroll
            for (int o = 0; o < 8; o++){
                const float tot = atomicAdd(&acc[o], 0.f);   // coherent read
                out[o] = fc_b[o] + tot * (1.0f / (float)NP);
            }
        }
    }
}

extern "C" void kernel_launch(void* const* d_in, const int* in_sizes, int n_in,
                              void* d_out, int out_size, void* d_ws, size_t ws_size,
                              hipStream_t stream)
{
    (void)in_sizes; (void)n_in; (void)out_size; (void)ws_size;
    const float* points   = (const float*)d_in[0];
    const float* l1_W1    = (const float*)d_in[1];
    const float* l1_B1    = (const float*)d_in[2];
    const float* l1_W2    = (const float*)d_in[3];
    const float* l1_B2    = (const float*)d_in[4];
    const float* l1_si0_w = (const float*)d_in[5];
    const float* l1_si0_b = (const float*)d_in[6];
    const float* l1_si1_w = (const float*)d_in[7];
    const float* l1_nl_b  = (const float*)d_in[8];
    const float* l2_W1    = (const float*)d_in[9];
    const float* l2_B1    = (const float*)d_in[10];
    const float* l2_W2    = (const float*)d_in[11];
    const float* l2_B2    = (const float*)d_in[12];
    const float* l2_si0_w = (const float*)d_in[13];
    const float* l2_si0_b = (const float*)d_in[14];
    // d_in[15] l2_si1_w, d_in[16] l2_nl_b: dead code in the reference readout
    const float* fc_w     = (const float*)d_in[17];
    const float* fc_b     = (const float*)d_in[18];

    float* ws    = (float*)d_ws;
    float* tab1d = ws;                 // 4*TT floats (packed float4 per node)
    float* tab2d = tab1d + 4*TT;       // 64*TT
    float* pts4  = tab2d + 64*TT;      // 4*NP
    float* xq    = pts4 + 4*NP;        // 4*NP*C
    float* acc   = xq + 4*NP*C;        // 8 pooled floats
    int*   counter = (int*)(acc + 8);  // completion counter (zeroed by k_tab)

    k_tab<<<37, 256, 0, stream>>>(points, l1_W1, l1_B1, l1_W2, l1_B2,
                                  l2_W1, l2_B1, l2_W2, l2_B2,
                                  tab1d, tab2d, pts4, acc);
    k_l1<<<NP, 256, 0, stream>>>(pts4, tab1d, l1_si0_w, l1_si0_b, l1_si1_w, l1_nl_b, xq);
    k_l2<<<NP, 256, 0, stream>>>(pts4, tab2d, xq, l2_si0_w, l2_si0_b,
                                 fc_w, fc_b, acc, counter, (float*)d_out);
}